// Round 8
// baseline (152.378 us; speedup 1.0000x reference)
//
#include <hip/hip_runtime.h>

// B=4, T=4096, E=1024, H=64.
// out = Q @ M_b,  M_b = (1/32) * K_b^T V_b,  Q/K/V = idx@W + b   (linear attention:
// reference applies no mask/softmax). Scale folded into Wk/bk.
//
// R8 experiment: R7 kernels unchanged; idx is first copied D2D (SDMA) into ws
// and qkv reads the copy. Probes the "d_in is a slow-for-shader-reads pool"
// theory behind the structure-independent ~1 TB/s read ceiling of R1-R7.

typedef __attribute__((ext_vector_type(8))) short bf16x8;   // 8 bf16 = 4 VGPRs
typedef __attribute__((ext_vector_type(4))) float f32x4;    // MFMA C/D

#define MFMA16(a, b, c) __builtin_amdgcn_mfma_f32_16x16x32_bf16((a), (b), (c), 0, 0, 0)

__device__ __forceinline__ unsigned short f2bf(float f) {
    unsigned int u = __float_as_uint(f);
    u += 0x7fffu + ((u >> 16) & 1u);          // round-to-nearest-even
    return (unsigned short)(u >> 16);
}

// ---------------------------------------------------------------------------
// K0: weights -> MFMA-fragment order.
// Chunk index t = (kk*12 + nt)*64 + lane holds 8 bf16:
//   W^T[n][k], n = nt*16 + (lane&15), k = kk*32 + (lane>>4)*8 + j.
// n<64 -> Wq, n<128 -> Wk * 1/32, else Wv.   (W is [k][h] in memory)
__global__ void prep(const float* __restrict__ Wq, const float* __restrict__ Wk,
                     const float* __restrict__ Wv, unsigned short* __restrict__ WB) {
    int t = blockIdx.x * 256 + threadIdx.x;   // 96 blocks -> 24576 chunks
    int kki = t / 768;
    int rem = t - kki * 768;
    int nt = rem >> 6, lane = rem & 63;
    int n = nt * 16 + (lane & 15);
    int kb = kki * 32 + ((lane >> 4) * 8);
    int mm = n >> 6, h = n & 63;
    const float* W = (mm == 0) ? Wq : (mm == 1) ? Wk : Wv;
    float sc = (mm == 1) ? 0.03125f : 1.0f;
    bf16x8 v;
    #pragma unroll
    for (int j = 0; j < 8; j++) v[j] = (short)f2bf(W[(size_t)(kb + j) * 64 + h] * sc);
    *(bf16x8*)(WB + (size_t)t * 8) = v;
}

// ---------------------------------------------------------------------------
// K1: fused QKV projection (identical to R7).
__global__ __launch_bounds__(256, 4) void qkv(
    const float* __restrict__ idx, const unsigned short* __restrict__ WB,
    const float* __restrict__ bq, const float* __restrict__ bk, const float* __restrict__ bv,
    unsigned short* __restrict__ Q, unsigned short* __restrict__ Kt,
    unsigned short* __restrict__ Vt) {
    __shared__ unsigned short As[16 * 1032];       // 33 KB
    const int lane = threadIdx.x & 63, w = threadIdx.x >> 6;
    const int r0 = blockIdx.x * 16;

    // ---- stage: contiguous 16KB per wave (4 rows) ----
    const float* src = idx + (size_t)(r0 + w * 4) * 1024;
    #pragma unroll
    for (int batch = 0; batch < 2; batch++) {
        float4 v[8];
        #pragma unroll
        for (int j = 0; j < 8; j++)
            v[j] = *(const float4*)(src + (size_t)(batch * 8 + j) * 256 + lane * 4);
        #pragma unroll
        for (int j = 0; j < 8; j++) {
            int i   = batch * 8 + j;
            int row = w * 4 + (i >> 2);            // 4 chunks of 256 floats per row
            int k   = (i & 3) * 256 + lane * 4;
            unsigned int lo = ((unsigned int)f2bf(v[j].y) << 16) | f2bf(v[j].x);
            unsigned int hi = ((unsigned int)f2bf(v[j].w) << 16) | f2bf(v[j].z);
            uint2 p; p.x = lo; p.y = hi;
            *(uint2*)(As + (size_t)row * 1032 + k) = p;
        }
    }
    __syncthreads();

    // ---- compute: software-pipelined (B 1 kk ahead in regs, A 1 kk ahead) ----
    const f32x4 z4 = {0.f, 0.f, 0.f, 0.f};
    f32x4 acc[3] = {z4, z4, z4};

    const unsigned short* a_base = As + (size_t)(lane & 15) * 1032 + ((lane >> 4) * 8);
    bf16x8 a_c = *(const bf16x8*)(a_base);
    bf16x8 bc[3], bn[3];
    {
        const unsigned short* Bp = WB + (size_t)(lane * 8);
        #pragma unroll
        for (int j = 0; j < 3; j++) bc[j] = *(const bf16x8*)(Bp + (w + j * 4) * 512);
    }
    for (int kk = 0; kk < 32; kk++) {
        bf16x8 a_n = a_c;
        if (kk < 31) {
            const unsigned short* Bp = WB + (size_t)(((kk + 1) * 12) * 64 + lane) * 8;
            #pragma unroll
            for (int j = 0; j < 3; j++) bn[j] = *(const bf16x8*)(Bp + (w + j * 4) * 512);
            a_n = *(const bf16x8*)(a_base + (kk + 1) * 32);
        }
        #pragma unroll
        for (int j = 0; j < 3; j++) acc[j] = MFMA16(a_c, bc[j], acc[j]);
        #pragma unroll
        for (int j = 0; j < 3; j++) bc[j] = bn[j];
        a_c = a_n;
    }

    // ---- epilogue via LDS transpose (As is dead) ----
    __syncthreads();                               // all A reads done
    unsigned short* Lq = As;                       // [16][64] row-major (1024)
    unsigned short* Lk = As + 1024;                // [64][16] h-major  (1024)
    unsigned short* Lv = As + 2048;                // [64][16] h-major  (1024)
    const int h   = w * 16 + (lane & 15);
    const int row = (lane >> 4) * 4;               // + reg
    {
        float bias0 = bq[h], bias1 = bk[h] * 0.03125f, bias2 = bv[h];
        #pragma unroll
        for (int reg = 0; reg < 4; reg++) {
            int r = row + reg;
            Lq[r * 64 + h] = f2bf(acc[0][reg] + bias0);
            Lk[h * 16 + r] = f2bf(acc[1][reg] + bias1);
            Lv[h * 16 + r] = f2bf(acc[2][reg] + bias2);
        }
    }
    __syncthreads();
    {
        const int tt = threadIdx.x;
        // Q: [16 rows][64 h], fully coalesced 8B/lane
        int qr = tt >> 4, qh = (tt & 15) * 4;
        *(uint2*)(Q + (size_t)(r0 + qr) * 64 + qh) = *(const uint2*)(Lq + qr * 64 + qh);
        // Kt/Vt: [h][t], 8B/lane, 4 lanes per h
        int b = r0 >> 12, t0 = r0 & 4095;
        int hh = tt >> 2, tc = (tt & 3) * 4;
        *(uint2*)(Kt + (size_t)b * 262144 + hh * 4096 + t0 + tc) =
            *(const uint2*)(Lk + hh * 16 + tc);
        *(uint2*)(Vt + (size_t)b * 262144 + hh * 4096 + t0 + tc) =
            *(const uint2*)(Lv + hh * 16 + tc);
    }
}

// ---------------------------------------------------------------------------
// K2: partial M over 32 T-chunks of 128: part[b][c] = Kt_chunk @ Vt_chunk^T (fp32)
__global__ __launch_bounds__(256) void ktv_partial(
    const unsigned short* __restrict__ Kt, const unsigned short* __restrict__ Vt,
    float* __restrict__ part) {
    const int lane = threadIdx.x & 63, wave = threadIdx.x >> 6;
    const int c = blockIdx.x, b = blockIdx.y;
    const unsigned short* Kb = Kt + (size_t)b * 262144;
    const unsigned short* Vb = Vt + (size_t)b * 262144;
    const f32x4 z4 = {0.f, 0.f, 0.f, 0.f};
    f32x4 acc[4] = {z4, z4, z4, z4};
    const int m  = 16 * wave + (lane & 15);
    const int tq = (lane >> 4) * 8;
    #pragma unroll
    for (int it = 0; it < 4; it++) {
        int t0 = c * 128 + it * 32 + tq;
        bf16x8 a = *(const bf16x8*)&Kb[(size_t)m * 4096 + t0];
        #pragma unroll
        for (int nt = 0; nt < 4; nt++) {
            bf16x8 bb = *(const bf16x8*)&Vb[(size_t)(nt * 16 + (lane & 15)) * 4096 + t0];
            acc[nt] = MFMA16(a, bb, acc[nt]);
        }
    }
    float* P = part + (size_t)(b * 32 + c) * 4096;
    const int rowb = 16 * wave + (lane >> 4) * 4;
    #pragma unroll
    for (int nt = 0; nt < 4; nt++)
        #pragma unroll
        for (int reg = 0; reg < 4; reg++)
            P[(rowb + reg) * 64 + nt * 16 + (lane & 15)] = acc[nt][reg];
}

// ---------------------------------------------------------------------------
// K3: M reduce over 32 chunks; store TRANSPOSED bf16: Mt[b][h2][h1]
__global__ void reduce_m(const float* __restrict__ part,
                         unsigned short* __restrict__ Mt) {
    int i = blockIdx.x * 256 + threadIdx.x;         // 16384 -> grid 64
    int b = i >> 12, h1 = (i >> 6) & 63, h2 = i & 63;
    float s = 0.f;
    #pragma unroll
    for (int cc = 0; cc < 32; cc++)
        s += part[(size_t)(b * 32 + cc) * 4096 + h1 * 64 + h2];
    Mt[(size_t)b * 4096 + h2 * 64 + h1] = f2bf(s);
}

// ---------------------------------------------------------------------------
// K4: out[r][h2] = Q[r][:] @ M_b[:, h2], fp32 out.
__global__ __launch_bounds__(256) void qm(
    const unsigned short* __restrict__ Q, const unsigned short* __restrict__ Mt,
    float* __restrict__ out) {
    const int lane = threadIdx.x & 63, wave = threadIdx.x >> 6;
    const int r0 = blockIdx.x * 64;
    const int b  = r0 >> 12;
    const f32x4 z4 = {0.f, 0.f, 0.f, 0.f};
    f32x4 acc[4] = {z4, z4, z4, z4};
    const int rr = r0 + 16 * wave + (lane & 15);
    const int kq = (lane >> 4) * 8;
    #pragma unroll
    for (int ks = 0; ks < 2; ks++) {
        int k0 = ks * 32;
        bf16x8 a = *(const bf16x8*)&Q[(size_t)rr * 64 + k0 + kq];
        #pragma unroll
        for (int nt = 0; nt < 4; nt++) {
            bf16x8 bb = *(const bf16x8*)&Mt[(size_t)b * 4096 + (nt * 16 + (lane & 15)) * 64 + k0 + kq];
            acc[nt] = MFMA16(a, bb, acc[nt]);
        }
    }
    const int rowb = r0 + 16 * wave + (lane >> 4) * 4;
    #pragma unroll
    for (int nt = 0; nt < 4; nt++)
        #pragma unroll
        for (int reg = 0; reg < 4; reg++)
            out[(size_t)(rowb + reg) * 64 + nt * 16 + (lane & 15)] = acc[nt][reg];
}

// ---------------------------------------------------------------------------
// Workspace layout:
//   [0, 384K)      WB    (dead after qkv)
//   [0, 2M)        Pp    (written by ktv_partial AFTER qkv -> safe reuse of WB)
//   [2M, 4M)       Q
//   [4M, 6M)       Kt
//   [6M, 8M)       Vt
//   [8M, 8M+32K)   Mt
//   [16M, 80M)     idxC  (SDMA copy of idx; 64 MB)
extern "C" void kernel_launch(void* const* d_in, const int* in_sizes, int n_in,
                              void* d_out, int out_size, void* d_ws, size_t ws_size,
                              hipStream_t stream) {
    const float* idx = (const float*)d_in[0];
    const float* Wq  = (const float*)d_in[1];
    const float* bq  = (const float*)d_in[2];
    const float* Wk  = (const float*)d_in[3];
    const float* bk  = (const float*)d_in[4];
    const float* Wv  = (const float*)d_in[5];
    const float* bv  = (const float*)d_in[6];
    float* out = (float*)d_out;

    char* ws = (char*)d_ws;
    unsigned short* WB   = (unsigned short*)(ws);
    float*          Pp   = (float*)(ws);
    unsigned short* Q    = (unsigned short*)(ws + (2048u << 10));
    unsigned short* Kt   = (unsigned short*)(ws + (4096u << 10));
    unsigned short* Vt   = (unsigned short*)(ws + (6144u << 10));
    unsigned short* Mt   = (unsigned short*)(ws + (8192u << 10));
    float*          idxC = (float*)(ws + ((size_t)16384u << 10));

    // Probe: move idx to ordinary ws memory via the SDMA path (harness-allowed).
    hipMemcpyAsync(idxC, idx, (size_t)4 * 4096 * 1024 * sizeof(float),
                   hipMemcpyDeviceToDevice, stream);

    hipLaunchKernelGGL(prep,        dim3(96),     dim3(256), 0, stream, Wq, Wk, Wv, WB);
    hipLaunchKernelGGL(qkv,         dim3(1024),   dim3(256), 0, stream,
                       idxC, WB, bq, bk, bv, Q, Kt, Vt);
    hipLaunchKernelGGL(ktv_partial, dim3(32, 4),  dim3(256), 0, stream, Kt, Vt, Pp);
    hipLaunchKernelGGL(reduce_m,    dim3(64),     dim3(256), 0, stream, Pp, Mt);
    hipLaunchKernelGGL(qm,          dim3(256),    dim3(256), 0, stream, Q, Mt, out);
}

// Round 9
// 136.523 us; speedup vs baseline: 1.1161x; 1.1161x over previous
//
#include <hip/hip_runtime.h>

// B=4, T=4096, E=1024, H=64.
// out = Q @ M_b,  M_b = (1/32) * K_b^T V_b,  Q/K/V = idx@W + b   (linear attention:
// reference applies no mask/softmax). Scale folded into Wk/bk.
//
// R9: split the heavy read into a PURE STREAMING fp32->bf16 convert kernel
// (m13/fillBuffer shape: grid-stride, no LDS, no barriers, tiny VGPR), fused
// with prep. qkv stages bf16 (half bytes, L3-hot) and is otherwise R7.

typedef __attribute__((ext_vector_type(8))) short bf16x8;   // 8 bf16 = 4 VGPRs
typedef __attribute__((ext_vector_type(4))) float f32x4;    // MFMA C/D

#define MFMA16(a, b, c) __builtin_amdgcn_mfma_f32_16x16x32_bf16((a), (b), (c), 0, 0, 0)

__device__ __forceinline__ unsigned short f2bf(float f) {
    unsigned int u = __float_as_uint(f);
    u += 0x7fffu + ((u >> 16) & 1u);          // round-to-nearest-even
    return (unsigned short)(u >> 16);
}
__device__ __forceinline__ unsigned int pack2(float a, float b) {
    return ((unsigned int)f2bf(b) << 16) | f2bf(a);
}

// ---------------------------------------------------------------------------
// K0: fused  (a) weights -> MFMA-fragment order WB   [blocks 0..95]
//            (b) pure streaming idx fp32 -> bf16     [blocks 96..96+8191]
// cvt shape mirrors the 6.5 TB/s fill kernel: 1 float4 load -> 1 uint2 store,
// x2 per thread, perfectly coalesced, no LDS, no barrier.
__global__ __launch_bounds__(256) void prep_cvt(
    const float* __restrict__ Wq, const float* __restrict__ Wk,
    const float* __restrict__ Wv, unsigned short* __restrict__ WB,
    const float* __restrict__ idx, unsigned short* __restrict__ idxB) {
    if (blockIdx.x < 96) {
        int t = blockIdx.x * 256 + threadIdx.x;   // 24576 chunks
        int kki = t / 768;
        int rem = t - kki * 768;
        int nt = rem >> 6, lane = rem & 63;
        int n = nt * 16 + (lane & 15);
        int kb = kki * 32 + ((lane >> 4) * 8);
        int mm = n >> 6, h = n & 63;
        const float* W = (mm == 0) ? Wq : (mm == 1) ? Wk : Wv;
        float sc = (mm == 1) ? 0.03125f : 1.0f;
        bf16x8 v;
        #pragma unroll
        for (int j = 0; j < 8; j++) v[j] = (short)f2bf(W[(size_t)(kb + j) * 64 + h] * sc);
        *(bf16x8*)(WB + (size_t)t * 8) = v;
    } else {
        size_t f0 = (size_t)(blockIdx.x - 96) * 512 + threadIdx.x;  // float4 index
        const float4* s = (const float4*)idx;
        uint2* d = (uint2*)idxB;
        float4 a = s[f0];
        float4 b = s[f0 + 256];
        uint2 pa, pb;
        pa.x = pack2(a.x, a.y); pa.y = pack2(a.z, a.w);
        pb.x = pack2(b.x, b.y); pb.y = pack2(b.z, b.w);
        d[f0]       = pa;
        d[f0 + 256] = pb;
    }
}

// ---------------------------------------------------------------------------
// K1: fused QKV projection (R7 structure; stages bf16 from idxB).
// Block = 16 rows, 4 waves; grid 1024 (4 blocks/CU).
// Stage: wave w copies rows [4w,4w+4) of idxB (8KB, 1KB-contiguous per instr)
// into LDS (row stride 1032 shorts). Compute: 32 kk, B reg-double-buffered,
// A ds_read prefetched 1 ahead. Epilogue: LDS transpose -> coalesced stores.
__global__ __launch_bounds__(256, 4) void qkv(
    const unsigned short* __restrict__ idxB, const unsigned short* __restrict__ WB,
    const float* __restrict__ bq, const float* __restrict__ bk, const float* __restrict__ bv,
    unsigned short* __restrict__ Q, unsigned short* __restrict__ Kt,
    unsigned short* __restrict__ Vt) {
    __shared__ unsigned short As[16 * 1032];       // 33 KB
    const int lane = threadIdx.x & 63, w = threadIdx.x >> 6;
    const int r0 = blockIdx.x * 16;

    // ---- stage: 8KB contiguous per wave ----
    {
        const unsigned short* src = idxB + (size_t)(r0 + w * 4) * 1024;
        bf16x8 v[8];
        #pragma unroll
        for (int i = 0; i < 8; i++)
            v[i] = *(const bf16x8*)(src + (size_t)(i >> 1) * 1024 + (i & 1) * 512 + lane * 8);
        #pragma unroll
        for (int i = 0; i < 8; i++)
            *(bf16x8*)(As + (size_t)(w * 4 + (i >> 1)) * 1032 + (i & 1) * 512 + lane * 8) = v[i];
    }
    __syncthreads();

    // ---- compute: software-pipelined (B 1 kk ahead in regs, A 1 kk ahead) ----
    const f32x4 z4 = {0.f, 0.f, 0.f, 0.f};
    f32x4 acc[3] = {z4, z4, z4};

    const unsigned short* a_base = As + (size_t)(lane & 15) * 1032 + ((lane >> 4) * 8);
    bf16x8 a_c = *(const bf16x8*)(a_base);
    bf16x8 bc[3], bn[3];
    {
        const unsigned short* Bp = WB + (size_t)(lane * 8);
        #pragma unroll
        for (int j = 0; j < 3; j++) bc[j] = *(const bf16x8*)(Bp + (w + j * 4) * 512);
    }
    for (int kk = 0; kk < 32; kk++) {
        bf16x8 a_n = a_c;
        if (kk < 31) {
            const unsigned short* Bp = WB + (size_t)(((kk + 1) * 12) * 64 + lane) * 8;
            #pragma unroll
            for (int j = 0; j < 3; j++) bn[j] = *(const bf16x8*)(Bp + (w + j * 4) * 512);
            a_n = *(const bf16x8*)(a_base + (kk + 1) * 32);
        }
        #pragma unroll
        for (int j = 0; j < 3; j++) acc[j] = MFMA16(a_c, bc[j], acc[j]);
        #pragma unroll
        for (int j = 0; j < 3; j++) bc[j] = bn[j];
        a_c = a_n;
    }

    // ---- epilogue via LDS transpose (As is dead) ----
    __syncthreads();                               // all A reads done
    unsigned short* Lq = As;                       // [16][64] row-major (1024)
    unsigned short* Lk = As + 1024;                // [64][16] h-major  (1024)
    unsigned short* Lv = As + 2048;                // [64][16] h-major  (1024)
    const int h   = w * 16 + (lane & 15);
    const int row = (lane >> 4) * 4;               // + reg
    {
        float bias0 = bq[h], bias1 = bk[h] * 0.03125f, bias2 = bv[h];
        #pragma unroll
        for (int reg = 0; reg < 4; reg++) {
            int r = row + reg;
            Lq[r * 64 + h] = f2bf(acc[0][reg] + bias0);
            Lk[h * 16 + r] = f2bf(acc[1][reg] + bias1);
            Lv[h * 16 + r] = f2bf(acc[2][reg] + bias2);
        }
    }
    __syncthreads();
    {
        const int tt = threadIdx.x;
        // Q: [16 rows][64 h], fully coalesced 8B/lane
        int qr = tt >> 4, qh = (tt & 15) * 4;
        *(uint2*)(Q + (size_t)(r0 + qr) * 64 + qh) = *(const uint2*)(Lq + qr * 64 + qh);
        // Kt/Vt: [h][t], 8B/lane, 4 lanes per h
        int b = r0 >> 12, t0 = r0 & 4095;
        int hh = tt >> 2, tc = (tt & 3) * 4;
        *(uint2*)(Kt + (size_t)b * 262144 + hh * 4096 + t0 + tc) =
            *(const uint2*)(Lk + hh * 16 + tc);
        *(uint2*)(Vt + (size_t)b * 262144 + hh * 4096 + t0 + tc) =
            *(const uint2*)(Lv + hh * 16 + tc);
    }
}

// ---------------------------------------------------------------------------
// K2: partial M over 32 T-chunks of 128: part[b][c] = Kt_chunk @ Vt_chunk^T (fp32)
__global__ __launch_bounds__(256) void ktv_partial(
    const unsigned short* __restrict__ Kt, const unsigned short* __restrict__ Vt,
    float* __restrict__ part) {
    const int lane = threadIdx.x & 63, wave = threadIdx.x >> 6;
    const int c = blockIdx.x, b = blockIdx.y;
    const unsigned short* Kb = Kt + (size_t)b * 262144;
    const unsigned short* Vb = Vt + (size_t)b * 262144;
    const f32x4 z4 = {0.f, 0.f, 0.f, 0.f};
    f32x4 acc[4] = {z4, z4, z4, z4};
    const int m  = 16 * wave + (lane & 15);
    const int tq = (lane >> 4) * 8;
    #pragma unroll
    for (int it = 0; it < 4; it++) {
        int t0 = c * 128 + it * 32 + tq;
        bf16x8 a = *(const bf16x8*)&Kb[(size_t)m * 4096 + t0];
        #pragma unroll
        for (int nt = 0; nt < 4; nt++) {
            bf16x8 bb = *(const bf16x8*)&Vb[(size_t)(nt * 16 + (lane & 15)) * 4096 + t0];
            acc[nt] = MFMA16(a, bb, acc[nt]);
        }
    }
    float* P = part + (size_t)(b * 32 + c) * 4096;
    const int rowb = 16 * wave + (lane >> 4) * 4;
    #pragma unroll
    for (int nt = 0; nt < 4; nt++)
        #pragma unroll
        for (int reg = 0; reg < 4; reg++)
            P[(rowb + reg) * 64 + nt * 16 + (lane & 15)] = acc[nt][reg];
}

// ---------------------------------------------------------------------------
// K3: M reduce over 32 chunks; store TRANSPOSED bf16: Mt[b][h2][h1]
__global__ void reduce_m(const float* __restrict__ part,
                         unsigned short* __restrict__ Mt) {
    int i = blockIdx.x * 256 + threadIdx.x;         // 16384 -> grid 64
    int b = i >> 12, h1 = (i >> 6) & 63, h2 = i & 63;
    float s = 0.f;
    #pragma unroll
    for (int cc = 0; cc < 32; cc++)
        s += part[(size_t)(b * 32 + cc) * 4096 + h1 * 64 + h2];
    Mt[(size_t)b * 4096 + h2 * 64 + h1] = f2bf(s);
}

// ---------------------------------------------------------------------------
// K4: out[r][h2] = Q[r][:] @ M_b[:, h2], fp32 out.
__global__ __launch_bounds__(256) void qm(
    const unsigned short* __restrict__ Q, const unsigned short* __restrict__ Mt,
    float* __restrict__ out) {
    const int lane = threadIdx.x & 63, wave = threadIdx.x >> 6;
    const int r0 = blockIdx.x * 64;
    const int b  = r0 >> 12;
    const f32x4 z4 = {0.f, 0.f, 0.f, 0.f};
    f32x4 acc[4] = {z4, z4, z4, z4};
    const int rr = r0 + 16 * wave + (lane & 15);
    const int kq = (lane >> 4) * 8;
    #pragma unroll
    for (int ks = 0; ks < 2; ks++) {
        int k0 = ks * 32;
        bf16x8 a = *(const bf16x8*)&Q[(size_t)rr * 64 + k0 + kq];
        #pragma unroll
        for (int nt = 0; nt < 4; nt++) {
            bf16x8 bb = *(const bf16x8*)&Mt[(size_t)b * 4096 + (nt * 16 + (lane & 15)) * 64 + k0 + kq];
            acc[nt] = MFMA16(a, bb, acc[nt]);
        }
    }
    const int rowb = r0 + 16 * wave + (lane >> 4) * 4;
    #pragma unroll
    for (int nt = 0; nt < 4; nt++)
        #pragma unroll
        for (int reg = 0; reg < 4; reg++)
            out[(size_t)(rowb + reg) * 64 + nt * 16 + (lane & 15)] = acc[nt][reg];
}

// ---------------------------------------------------------------------------
// Workspace layout:
//   [0, 384K)      WB    (dead after qkv)
//   [0, 2M)        Pp    (written by ktv_partial AFTER qkv -> safe reuse of WB)
//   [2M, 4M)       Q
//   [4M, 6M)       Kt
//   [6M, 8M)       Vt
//   [8M, 8M+32K)   Mt
//   [16M, 48M)     idxB  (bf16 idx, 32 MB)
extern "C" void kernel_launch(void* const* d_in, const int* in_sizes, int n_in,
                              void* d_out, int out_size, void* d_ws, size_t ws_size,
                              hipStream_t stream) {
    const float* idx = (const float*)d_in[0];
    const float* Wq  = (const float*)d_in[1];
    const float* bq  = (const float*)d_in[2];
    const float* Wk  = (const float*)d_in[3];
    const float* bk  = (const float*)d_in[4];
    const float* Wv  = (const float*)d_in[5];
    const float* bv  = (const float*)d_in[6];
    float* out = (float*)d_out;

    char* ws = (char*)d_ws;
    unsigned short* WB   = (unsigned short*)(ws);
    float*          Pp   = (float*)(ws);
    unsigned short* Q    = (unsigned short*)(ws + (2048u << 10));
    unsigned short* Kt   = (unsigned short*)(ws + (4096u << 10));
    unsigned short* Vt   = (unsigned short*)(ws + (6144u << 10));
    unsigned short* Mt   = (unsigned short*)(ws + (8192u << 10));
    unsigned short* idxB = (unsigned short*)(ws + ((size_t)16384u << 10));

    hipLaunchKernelGGL(prep_cvt,    dim3(96 + 8192), dim3(256), 0, stream,
                       Wq, Wk, Wv, WB, idx, idxB);
    hipLaunchKernelGGL(qkv,         dim3(1024),   dim3(256), 0, stream,
                       idxB, WB, bq, bk, bv, Q, Kt, Vt);
    hipLaunchKernelGGL(ktv_partial, dim3(32, 4),  dim3(256), 0, stream, Kt, Vt, Pp);
    hipLaunchKernelGGL(reduce_m,    dim3(64),     dim3(256), 0, stream, Pp, Mt);
    hipLaunchKernelGGL(qm,          dim3(256),    dim3(256), 0, stream, Q, Mt, out);
}

// Round 10
// 125.782 us; speedup vs baseline: 1.2115x; 1.0854x over previous
//
#include <hip/hip_runtime.h>

// B=4, T=4096, E=1024, H=64.
// out = Q @ M_b,  M_b = (1/32) * K_b^T V_b,  Q/K/V = idx@W + b   (linear attention:
// reference applies no mask/softmax). Scale folded into Wk/bk.
//
// R10 = R7 reverted (best: 125.6 us). R8 (SDMA copy) and R9 (pure-stream cvt)
// controls proved the ~1.8 TB/s shader-read cap is environmental; R7's qkv sits
// on that floor (64 MB idx read ~= 35 us). See round notes.

typedef __attribute__((ext_vector_type(8))) short bf16x8;   // 8 bf16 = 4 VGPRs
typedef __attribute__((ext_vector_type(4))) float f32x4;    // MFMA C/D

#define MFMA16(a, b, c) __builtin_amdgcn_mfma_f32_16x16x32_bf16((a), (b), (c), 0, 0, 0)

__device__ __forceinline__ unsigned short f2bf(float f) {
    unsigned int u = __float_as_uint(f);
    u += 0x7fffu + ((u >> 16) & 1u);          // round-to-nearest-even
    return (unsigned short)(u >> 16);
}

// ---------------------------------------------------------------------------
// K0: weights -> MFMA-fragment order.
// Chunk index t = (kk*12 + nt)*64 + lane holds 8 bf16:
//   W^T[n][k], n = nt*16 + (lane&15), k = kk*32 + (lane>>4)*8 + j.
// n<64 -> Wq, n<128 -> Wk * 1/32, else Wv.   (W is [k][h] in memory)
__global__ void prep(const float* __restrict__ Wq, const float* __restrict__ Wk,
                     const float* __restrict__ Wv, unsigned short* __restrict__ WB) {
    int t = blockIdx.x * 256 + threadIdx.x;   // 96 blocks -> 24576 chunks
    int kki = t / 768;
    int rem = t - kki * 768;
    int nt = rem >> 6, lane = rem & 63;
    int n = nt * 16 + (lane & 15);
    int kb = kki * 32 + ((lane >> 4) * 8);
    int mm = n >> 6, h = n & 63;
    const float* W = (mm == 0) ? Wq : (mm == 1) ? Wk : Wv;
    float sc = (mm == 1) ? 0.03125f : 1.0f;
    bf16x8 v;
    #pragma unroll
    for (int j = 0; j < 8; j++) v[j] = (short)f2bf(W[(size_t)(kb + j) * 64 + h] * sc);
    *(bf16x8*)(WB + (size_t)t * 8) = v;
}

// ---------------------------------------------------------------------------
// K1: fused QKV projection.
// Block = 16 rows (contiguous 64KB of idx), 4 waves; grid 1024 (4 blocks/CU).
// Stage: wave w reads rows [4w,4w+4) sequentially, 8 float4 in flight/batch,
// cast to bf16, ds_write (row stride 1032 shorts -> benign 2-way banks).
// Compute: 32 kk; per kk: 1 A ds_read_b128 (prefetched 1 ahead) + 3 B 1KB
// L2 loads (register double-buffered, issued a full kk ahead) + 3 MFMAs.
// Epilogue: accs -> LDS (reusing As) -> coalesced 8B/lane stores of Q/Kt/Vt.
__global__ __launch_bounds__(256, 4) void qkv(
    const float* __restrict__ idx, const unsigned short* __restrict__ WB,
    const float* __restrict__ bq, const float* __restrict__ bk, const float* __restrict__ bv,
    unsigned short* __restrict__ Q, unsigned short* __restrict__ Kt,
    unsigned short* __restrict__ Vt) {
    __shared__ unsigned short As[16 * 1032];       // 33 KB
    const int lane = threadIdx.x & 63, w = threadIdx.x >> 6;
    const int r0 = blockIdx.x * 16;

    // ---- stage: contiguous 16KB per wave (4 rows) ----
    const float* src = idx + (size_t)(r0 + w * 4) * 1024;
    #pragma unroll
    for (int batch = 0; batch < 2; batch++) {
        float4 v[8];
        #pragma unroll
        for (int j = 0; j < 8; j++)
            v[j] = *(const float4*)(src + (size_t)(batch * 8 + j) * 256 + lane * 4);
        #pragma unroll
        for (int j = 0; j < 8; j++) {
            int i   = batch * 8 + j;
            int row = w * 4 + (i >> 2);            // 4 chunks of 256 floats per row
            int k   = (i & 3) * 256 + lane * 4;
            unsigned int lo = ((unsigned int)f2bf(v[j].y) << 16) | f2bf(v[j].x);
            unsigned int hi = ((unsigned int)f2bf(v[j].w) << 16) | f2bf(v[j].z);
            uint2 p; p.x = lo; p.y = hi;
            *(uint2*)(As + (size_t)row * 1032 + k) = p;
        }
    }
    __syncthreads();

    // ---- compute: software-pipelined (B 1 kk ahead in regs, A 1 kk ahead) ----
    const f32x4 z4 = {0.f, 0.f, 0.f, 0.f};
    f32x4 acc[3] = {z4, z4, z4};

    const unsigned short* a_base = As + (size_t)(lane & 15) * 1032 + ((lane >> 4) * 8);
    bf16x8 a_c = *(const bf16x8*)(a_base);
    bf16x8 bc[3], bn[3];
    {
        const unsigned short* Bp = WB + (size_t)(lane * 8);
        #pragma unroll
        for (int j = 0; j < 3; j++) bc[j] = *(const bf16x8*)(Bp + (w + j * 4) * 512);
    }
    for (int kk = 0; kk < 32; kk++) {
        bf16x8 a_n = a_c;
        if (kk < 31) {
            const unsigned short* Bp = WB + (size_t)(((kk + 1) * 12) * 64 + lane) * 8;
            #pragma unroll
            for (int j = 0; j < 3; j++) bn[j] = *(const bf16x8*)(Bp + (w + j * 4) * 512);
            a_n = *(const bf16x8*)(a_base + (kk + 1) * 32);
        }
        #pragma unroll
        for (int j = 0; j < 3; j++) acc[j] = MFMA16(a_c, bc[j], acc[j]);
        #pragma unroll
        for (int j = 0; j < 3; j++) bc[j] = bn[j];
        a_c = a_n;
    }

    // ---- epilogue via LDS transpose (As is dead) ----
    __syncthreads();                               // all A reads done
    unsigned short* Lq = As;                       // [16][64] row-major (1024)
    unsigned short* Lk = As + 1024;                // [64][16] h-major  (1024)
    unsigned short* Lv = As + 2048;                // [64][16] h-major  (1024)
    const int h   = w * 16 + (lane & 15);
    const int row = (lane >> 4) * 4;               // + reg
    {
        float bias0 = bq[h], bias1 = bk[h] * 0.03125f, bias2 = bv[h];
        #pragma unroll
        for (int reg = 0; reg < 4; reg++) {
            int r = row + reg;
            Lq[r * 64 + h] = f2bf(acc[0][reg] + bias0);
            Lk[h * 16 + r] = f2bf(acc[1][reg] + bias1);
            Lv[h * 16 + r] = f2bf(acc[2][reg] + bias2);
        }
    }
    __syncthreads();
    {
        const int tt = threadIdx.x;
        // Q: [16 rows][64 h], fully coalesced 8B/lane
        int qr = tt >> 4, qh = (tt & 15) * 4;
        *(uint2*)(Q + (size_t)(r0 + qr) * 64 + qh) = *(const uint2*)(Lq + qr * 64 + qh);
        // Kt/Vt: [h][t], 8B/lane, 4 lanes per h
        int b = r0 >> 12, t0 = r0 & 4095;
        int hh = tt >> 2, tc = (tt & 3) * 4;
        *(uint2*)(Kt + (size_t)b * 262144 + hh * 4096 + t0 + tc) =
            *(const uint2*)(Lk + hh * 16 + tc);
        *(uint2*)(Vt + (size_t)b * 262144 + hh * 4096 + t0 + tc) =
            *(const uint2*)(Lv + hh * 16 + tc);
    }
}

// ---------------------------------------------------------------------------
// K2: partial M over 32 T-chunks of 128: part[b][c] = Kt_chunk @ Vt_chunk^T (fp32)
__global__ __launch_bounds__(256) void ktv_partial(
    const unsigned short* __restrict__ Kt, const unsigned short* __restrict__ Vt,
    float* __restrict__ part) {
    const int lane = threadIdx.x & 63, wave = threadIdx.x >> 6;
    const int c = blockIdx.x, b = blockIdx.y;
    const unsigned short* Kb = Kt + (size_t)b * 262144;
    const unsigned short* Vb = Vt + (size_t)b * 262144;
    const f32x4 z4 = {0.f, 0.f, 0.f, 0.f};
    f32x4 acc[4] = {z4, z4, z4, z4};
    const int m  = 16 * wave + (lane & 15);
    const int tq = (lane >> 4) * 8;
    #pragma unroll
    for (int it = 0; it < 4; it++) {
        int t0 = c * 128 + it * 32 + tq;
        bf16x8 a = *(const bf16x8*)&Kb[(size_t)m * 4096 + t0];
        #pragma unroll
        for (int nt = 0; nt < 4; nt++) {
            bf16x8 bb = *(const bf16x8*)&Vb[(size_t)(nt * 16 + (lane & 15)) * 4096 + t0];
            acc[nt] = MFMA16(a, bb, acc[nt]);
        }
    }
    float* P = part + (size_t)(b * 32 + c) * 4096;
    const int rowb = 16 * wave + (lane >> 4) * 4;
    #pragma unroll
    for (int nt = 0; nt < 4; nt++)
        #pragma unroll
        for (int reg = 0; reg < 4; reg++)
            P[(rowb + reg) * 64 + nt * 16 + (lane & 15)] = acc[nt][reg];
}

// ---------------------------------------------------------------------------
// K3: M reduce over 32 chunks; store TRANSPOSED bf16: Mt[b][h2][h1]
__global__ void reduce_m(const float* __restrict__ part,
                         unsigned short* __restrict__ Mt) {
    int i = blockIdx.x * 256 + threadIdx.x;         // 16384 -> grid 64
    int b = i >> 12, h1 = (i >> 6) & 63, h2 = i & 63;
    float s = 0.f;
    #pragma unroll
    for (int cc = 0; cc < 32; cc++)
        s += part[(size_t)(b * 32 + cc) * 4096 + h1 * 64 + h2];
    Mt[(size_t)b * 4096 + h2 * 64 + h1] = f2bf(s);
}

// ---------------------------------------------------------------------------
// K4: out[r][h2] = Q[r][:] @ M_b[:, h2], fp32 out.
__global__ __launch_bounds__(256) void qm(
    const unsigned short* __restrict__ Q, const unsigned short* __restrict__ Mt,
    float* __restrict__ out) {
    const int lane = threadIdx.x & 63, wave = threadIdx.x >> 6;
    const int r0 = blockIdx.x * 64;
    const int b  = r0 >> 12;
    const f32x4 z4 = {0.f, 0.f, 0.f, 0.f};
    f32x4 acc[4] = {z4, z4, z4, z4};
    const int rr = r0 + 16 * wave + (lane & 15);
    const int kq = (lane >> 4) * 8;
    #pragma unroll
    for (int ks = 0; ks < 2; ks++) {
        int k0 = ks * 32;
        bf16x8 a = *(const bf16x8*)&Q[(size_t)rr * 64 + k0 + kq];
        #pragma unroll
        for (int nt = 0; nt < 4; nt++) {
            bf16x8 bb = *(const bf16x8*)&Mt[(size_t)b * 4096 + (nt * 16 + (lane & 15)) * 64 + k0 + kq];
            acc[nt] = MFMA16(a, bb, acc[nt]);
        }
    }
    const int rowb = r0 + 16 * wave + (lane >> 4) * 4;
    #pragma unroll
    for (int nt = 0; nt < 4; nt++)
        #pragma unroll
        for (int reg = 0; reg < 4; reg++)
            out[(size_t)(rowb + reg) * 64 + nt * 16 + (lane & 15)] = acc[nt][reg];
}

// ---------------------------------------------------------------------------
// Workspace layout:
//   [0, 384K)    WB   (dead after qkv)
//   [0, 2M)      Pp   (written by ktv_partial AFTER qkv -> safe reuse of WB)
//   [2M, 4M)     Q
//   [4M, 6M)     Kt
//   [6M, 8M)     Vt
//   [8M, 8M+32K) Mt
extern "C" void kernel_launch(void* const* d_in, const int* in_sizes, int n_in,
                              void* d_out, int out_size, void* d_ws, size_t ws_size,
                              hipStream_t stream) {
    const float* idx = (const float*)d_in[0];
    const float* Wq  = (const float*)d_in[1];
    const float* bq  = (const float*)d_in[2];
    const float* Wk  = (const float*)d_in[3];
    const float* bk  = (const float*)d_in[4];
    const float* Wv  = (const float*)d_in[5];
    const float* bv  = (const float*)d_in[6];
    float* out = (float*)d_out;

    char* ws = (char*)d_ws;
    unsigned short* WB = (unsigned short*)(ws);
    float*          Pp = (float*)(ws);
    unsigned short* Q  = (unsigned short*)(ws + (2048u << 10));
    unsigned short* Kt = (unsigned short*)(ws + (4096u << 10));
    unsigned short* Vt = (unsigned short*)(ws + (6144u << 10));
    unsigned short* Mt = (unsigned short*)(ws + (8192u << 10));

    hipLaunchKernelGGL(prep,        dim3(96),     dim3(256), 0, stream, Wq, Wk, Wv, WB);
    hipLaunchKernelGGL(qkv,         dim3(1024),   dim3(256), 0, stream,
                       idx, WB, bq, bk, bv, Q, Kt, Vt);
    hipLaunchKernelGGL(ktv_partial, dim3(32, 4),  dim3(256), 0, stream, Kt, Vt, Pp);
    hipLaunchKernelGGL(reduce_m,    dim3(64),     dim3(256), 0, stream, Pp, Mt);
    hipLaunchKernelGGL(qm,          dim3(256),    dim3(256), 0, stream, Q, Mt, out);
}